// Round 7
// baseline (259.318 us; speedup 1.0000x reference)
//
#include <hip/hip_runtime.h>

// LJ constants (sigma=1, eps=1, cutoff=5)
// SHIFT = 4*((1/5)^12 - (1/5)^6)
__device__ __constant__ float kShift = 4.0f * (float)(1.0 / 244140625.0 - 1.0 / 15625.0);

#define GROUPS 3
#define MAX_MEMBERS 85             // 3*85 = 255 blocks, 1/CU
#define BUCKET 33334               // atoms per group; 133,336 B LDS
#define BLOCK_T 1024               // 16 waves
#define GDIV 10                    // first 1/10 of each slice -> global-atomic (EA) pipe

// Model (R3-R6 fit): LDS atomic unit = ~4 cyc per ACTIVE lane-add per CU
// (tight: 4.2/3.9/4.05 across very different configs). EA global-atomic pipe:
// ~20 G adds/s device-wide (R1), ~7.5 cyc/add wave-issue cost on the issuing
// CU (R6 decomposition), drain overlaps. R6 failed by CONCENTRATING the
// global adds on 1/3 of CUs; here every block offloads 1/10 of its own
// slice, partitioned among the 3 group-blocks by q%3 so each strip quad is
// emitted exactly once. LDS phase ~75us || EA ~64us device-wide.

__device__ __forceinline__ float lj_half_e(float x, float y, float z) {
    float r2 = x * x + y * y + z * z;
    float inv_r2 = __builtin_amdgcn_rcpf(r2);   // raw v_rcp_f32; tol is huge
    float sr6 = inv_r2 * inv_r2 * inv_r2;       // (sigma/r)^6
    float sr12 = sr6 * sr6;
    // 0.5 * (4*(sr12-sr6) - shift) = 2*(sr12-sr6) - 0.5*shift
    return __builtin_fmaf(sr12 - sr6, 2.0f, -0.5f * kShift);
}

__global__ __launch_bounds__(BLOCK_T) void lj_gather_split(
        const float* __restrict__ dist,
        const int* __restrict__ atom_a,
        const int* __restrict__ atom_b,
        float* __restrict__ ws,       // partials [GROUPS*members][BUCKET]
        float* __restrict__ gacc,     // global-atomic accumulator [n_atoms], pre-zeroed
        int members, int n_edges) {
    __shared__ float acc[BUCKET];

    const int g = blockIdx.x / members;     // group: atom-range owner
    const int m = blockIdx.x % members;     // slice: edge range
    const unsigned lo = (unsigned)(g * BUCKET);

    for (int i = threadIdx.x; i < BUCKET; i += BLOCK_T) acc[i] = 0.0f;
    __syncthreads();

    const long long quads = (long long)n_edges >> 2;
    const long long per = (quads + members - 1) / members;
    const long long q0 = (long long)m * per;
    const long long qe = (q0 + per < quads) ? (q0 + per) : quads;
    const long long span = (qe > q0) ? (qe - q0) : 0;
    const long long gq = span / GDIV;       // strip handled via EA pipe
    const long long gend = q0 + gq;

    // ---- Global strip: quads in [q0, q0+gq) with q%3 == g, this block only.
    // Every block (all 255) issues ~1/30 of its span globally -> even EA load.
    {
        long long rem = q0 % 3;
        long long need = (long long)g - rem;
        if (need < 0) need += 3;
        long long qs = q0 + need;           // first q in strip with q%3 == g
        for (long long q = qs + 3LL * threadIdx.x; q < gend; q += 3LL * BLOCK_T) {
            const float4* d4 = (const float4*)(dist) + (size_t)q * 3;
            float4 v0 = d4[0];
            float4 v1 = d4[1];
            float4 v2 = d4[2];
            int4 ia = ((const int4*)atom_a)[q];
            int4 ib = ((const int4*)atom_b)[q];
            float h0 = lj_half_e(v0.x, v0.y, v0.z);
            float h1 = lj_half_e(v0.w, v1.x, v1.y);
            float h2 = lj_half_e(v1.z, v1.w, v2.x);
            float h3 = lj_half_e(v2.y, v2.z, v2.w);
            atomicAdd(&gacc[ia.x], h0);
            atomicAdd(&gacc[ib.x], h0);
            atomicAdd(&gacc[ia.y], h1);
            atomicAdd(&gacc[ib.y], h1);
            atomicAdd(&gacc[ia.z], h2);
            atomicAdd(&gacc[ib.z], h2);
            atomicAdd(&gacc[ia.w], h3);
            atomicAdd(&gacc[ib.w], h3);
        }
    }

    // ---- LDS phase: quads in [q0+gq, qe), bucket-predicated ds_add.
    for (long long q = gend + threadIdx.x; q < qe; q += BLOCK_T) {
        const float4* d4 = (const float4*)(dist) + (size_t)q * 3;
        float4 v0 = d4[0];
        float4 v1 = d4[1];
        float4 v2 = d4[2];
        int4 ia = ((const int4*)atom_a)[q];
        int4 ib = ((const int4*)atom_b)[q];

        float h0 = lj_half_e(v0.x, v0.y, v0.z);
        float h1 = lj_half_e(v0.w, v1.x, v1.y);
        float h2 = lj_half_e(v1.z, v1.w, v2.x);
        float h3 = lj_half_e(v2.y, v2.z, v2.w);

        unsigned u;
        u = (unsigned)ia.x - lo; if (u < BUCKET) atomicAdd(&acc[u], h0);
        u = (unsigned)ib.x - lo; if (u < BUCKET) atomicAdd(&acc[u], h0);
        u = (unsigned)ia.y - lo; if (u < BUCKET) atomicAdd(&acc[u], h1);
        u = (unsigned)ib.y - lo; if (u < BUCKET) atomicAdd(&acc[u], h1);
        u = (unsigned)ia.z - lo; if (u < BUCKET) atomicAdd(&acc[u], h2);
        u = (unsigned)ib.z - lo; if (u < BUCKET) atomicAdd(&acc[u], h2);
        u = (unsigned)ia.w - lo; if (u < BUCKET) atomicAdd(&acc[u], h3);
        u = (unsigned)ib.w - lo; if (u < BUCKET) atomicAdd(&acc[u], h3);
    }

    // Edge-count tail (n_edges % 4 != 0): last slice, LDS path.
    if ((n_edges & 3) && m == members - 1) {
        for (long long e = quads * 4 + threadIdx.x; e < n_edges; e += BLOCK_T) {
            float x = dist[e * 3 + 0];
            float y = dist[e * 3 + 1];
            float z = dist[e * 3 + 2];
            float h = lj_half_e(x, y, z);
            unsigned u;
            u = (unsigned)atom_a[e] - lo; if (u < BUCKET) atomicAdd(&acc[u], h);
            u = (unsigned)atom_b[e] - lo; if (u < BUCKET) atomicAdd(&acc[u], h);
        }
    }
    __syncthreads();

    float* dst = ws + (size_t)(g * members + m) * BUCKET;
    for (int i = threadIdx.x; i < BUCKET; i += BLOCK_T) dst[i] = acc[i];
}

// out[a] = gacc[a] + sum over the `members` partials of a's group.
__global__ void reduce_groups(const float* __restrict__ ws,
                              const float* __restrict__ gacc,
                              float* __restrict__ out,
                              int members, int n_atoms) {
    int i = blockIdx.x * blockDim.x + threadIdx.x;
    if (i >= n_atoms) return;
    int g = i / BUCKET;
    int off = i - g * BUCKET;
    const float* base = ws + ((size_t)g * members) * BUCKET + off;
    float s = gacc[i];
    #pragma unroll 5
    for (int b = 0; b < members; ++b) s += base[(size_t)b * BUCKET];
    out[i] = s;
}

// Fallback (ws far too small): device-scope atomics straight into out. Slow but correct.
__global__ void lj_scatter_direct(const float* __restrict__ dist,
                                  const int* __restrict__ atom_a,
                                  const int* __restrict__ atom_b,
                                  float* __restrict__ out,
                                  int n_edges) {
    int t = blockIdx.x * blockDim.x + threadIdx.x;
    long long e0 = (long long)t * 4;
    if (e0 >= n_edges) return;
    if (e0 + 3 < n_edges) {
        const float4* d4 = (const float4*)(dist) + (size_t)t * 3;
        float4 v0 = d4[0];
        float4 v1 = d4[1];
        float4 v2 = d4[2];
        int4 ia = ((const int4*)atom_a)[t];
        int4 ib = ((const int4*)atom_b)[t];
        float h0 = lj_half_e(v0.x, v0.y, v0.z);
        float h1 = lj_half_e(v0.w, v1.x, v1.y);
        float h2 = lj_half_e(v1.z, v1.w, v2.x);
        float h3 = lj_half_e(v2.y, v2.z, v2.w);
        atomicAdd(&out[ia.x], h0);
        atomicAdd(&out[ib.x], h0);
        atomicAdd(&out[ia.y], h1);
        atomicAdd(&out[ib.y], h1);
        atomicAdd(&out[ia.z], h2);
        atomicAdd(&out[ib.z], h2);
        atomicAdd(&out[ia.w], h3);
        atomicAdd(&out[ib.w], h3);
    } else {
        for (long long e = e0; e < n_edges; ++e) {
            float x = dist[e * 3 + 0];
            float y = dist[e * 3 + 1];
            float z = dist[e * 3 + 2];
            float h = lj_half_e(x, y, z);
            atomicAdd(&out[atom_a[e]], h);
            atomicAdd(&out[atom_b[e]], h);
        }
    }
}

extern "C" void kernel_launch(void* const* d_in, const int* in_sizes, int n_in,
                              void* d_out, int out_size, void* d_ws, size_t ws_size,
                              hipStream_t stream) {
    const float* dist = (const float*)d_in[0];
    const int* atom_a = (const int*)d_in[1];
    const int* atom_b = (const int*)d_in[2];
    float* out = (float*)d_out;

    int n_edges = in_sizes[1];
    int n_atoms = out_size;

    // ws layout: partials [GROUPS*members][BUCKET] then gacc [n_atoms].
    size_t gacc_bytes = (size_t)n_atoms * sizeof(float);
    size_t per_member = (size_t)GROUPS * BUCKET * sizeof(float);
    size_t avail = (ws_size > gacc_bytes) ? (ws_size - gacc_bytes) : 0;
    int members = (int)(avail / per_member);
    if (members > MAX_MEMBERS) members = MAX_MEMBERS;
    bool range_ok = ((long long)GROUPS * BUCKET >= (long long)n_atoms);

    if (members >= 8 && range_ok) {
        float* ws = (float*)d_ws;
        float* gacc = ws + (size_t)GROUPS * members * BUCKET;
        hipMemsetAsync(gacc, 0, gacc_bytes, stream);
        lj_gather_split<<<GROUPS * members, BLOCK_T, 0, stream>>>(
            dist, atom_a, atom_b, ws, gacc, members, n_edges);
        int rblock = 256;
        int rgrid = (n_atoms + rblock - 1) / rblock;
        reduce_groups<<<rgrid, rblock, 0, stream>>>(ws, gacc, out, members, n_atoms);
    } else {
        hipMemsetAsync(d_out, 0, (size_t)n_atoms * sizeof(float), stream);
        int n_quads = (n_edges + 3) / 4;
        int block = 256;
        int grid = (n_quads + block - 1) / block;
        lj_scatter_direct<<<grid, block, 0, stream>>>(dist, atom_a, atom_b, out, n_edges);
    }
}

// Round 8
// 197.723 us; speedup vs baseline: 1.3115x; 1.3115x over previous
//
#include <hip/hip_runtime.h>

// LJ constants (sigma=1, eps=1, cutoff=5)
// SHIFT = 4*((1/5)^12 - (1/5)^6)
__device__ __constant__ float kShift = 4.0f * (float)(1.0 / 244140625.0 - 1.0 / 15625.0);

#define GROUPS 3
#define MAX_MEMBERS 85             // 3*85 = 255 blocks, 1 per CU
#define BUCKET 33334               // atoms per group; 133,336 B LDS
#define BLOCK_T 1024               // 16 waves

// Structural model (R3-R7): the LDS atomic unit processes scattered
// ds_add_f32 at ~4 cyc per ACTIVE lane-add per CU (fits 3.9-4.2 across five
// configs with 3x fetch-traffic and ILP variation). 12.8M adds / 255 CUs
// * 4 cyc => ~82 us floor; R4 measured 82.1. EA-offload hybrids (R6 conc.,
// R7 spread) both regressed >45%: global atomics share the vmem request
// path with the loads feeding the LDS phase. This kernel is the pure-LDS
// floor configuration.

__device__ __forceinline__ float lj_half_e(float x, float y, float z) {
    float r2 = x * x + y * y + z * z;
    float inv_r2 = __builtin_amdgcn_rcpf(r2);   // ~1e-5 rel err, tol is huge
    float sr6 = inv_r2 * inv_r2 * inv_r2;       // (sigma/r)^6
    float sr12 = sr6 * sr6;
    // 0.5 * (4*(sr12-sr6) - shift) = 2*(sr12-sr6) - 0.5*shift
    return __builtin_fmaf(sr12 - sr6, 2.0f, -0.5f * kShift);
}

__global__ __launch_bounds__(BLOCK_T) void lj_gather_group(
        const float* __restrict__ dist,
        const int* __restrict__ atom_a,
        const int* __restrict__ atom_b,
        float* __restrict__ ws,
        int members, int n_edges) {
    __shared__ float acc[BUCKET];

    const int g = blockIdx.x / members;     // atom-range owner
    const int m = blockIdx.x % members;     // edge slice
    const unsigned lo = (unsigned)(g * BUCKET);

    for (int i = threadIdx.x; i < BUCKET; i += BLOCK_T) acc[i] = 0.0f;
    __syncthreads();

    const long long quads = (long long)n_edges >> 2;
    const long long per = (quads + members - 1) / members;
    const long long q0 = (long long)m * per;
    const long long qe = (q0 + per < quads) ? (q0 + per) : quads;

    for (long long q = q0 + threadIdx.x; q < qe; q += BLOCK_T) {
        const float4* d4 = (const float4*)(dist) + (size_t)q * 3;
        float4 v0 = d4[0];
        float4 v1 = d4[1];
        float4 v2 = d4[2];
        int4 ia = ((const int4*)atom_a)[q];
        int4 ib = ((const int4*)atom_b)[q];

        float h0 = lj_half_e(v0.x, v0.y, v0.z);
        float h1 = lj_half_e(v0.w, v1.x, v1.y);
        float h2 = lj_half_e(v1.z, v1.w, v2.x);
        float h3 = lj_half_e(v2.y, v2.z, v2.w);

        unsigned u;
        u = (unsigned)ia.x - lo; if (u < BUCKET) atomicAdd(&acc[u], h0);
        u = (unsigned)ib.x - lo; if (u < BUCKET) atomicAdd(&acc[u], h0);
        u = (unsigned)ia.y - lo; if (u < BUCKET) atomicAdd(&acc[u], h1);
        u = (unsigned)ib.y - lo; if (u < BUCKET) atomicAdd(&acc[u], h1);
        u = (unsigned)ia.z - lo; if (u < BUCKET) atomicAdd(&acc[u], h2);
        u = (unsigned)ib.z - lo; if (u < BUCKET) atomicAdd(&acc[u], h2);
        u = (unsigned)ia.w - lo; if (u < BUCKET) atomicAdd(&acc[u], h3);
        u = (unsigned)ib.w - lo; if (u < BUCKET) atomicAdd(&acc[u], h3);
    }

    // Edge-count tail (n_edges % 4 != 0): last slice handles it.
    if ((n_edges & 3) && m == members - 1) {
        for (long long e = quads * 4 + threadIdx.x; e < n_edges; e += BLOCK_T) {
            float x = dist[e * 3 + 0];
            float y = dist[e * 3 + 1];
            float z = dist[e * 3 + 2];
            float h = lj_half_e(x, y, z);
            unsigned u;
            u = (unsigned)atom_a[e] - lo; if (u < BUCKET) atomicAdd(&acc[u], h);
            u = (unsigned)atom_b[e] - lo; if (u < BUCKET) atomicAdd(&acc[u], h);
        }
    }
    __syncthreads();

    float* dst = ws + (size_t)(g * members + m) * BUCKET;
    for (int i = threadIdx.x; i < BUCKET; i += BLOCK_T) dst[i] = acc[i];
}

// out[a] = sum over the `members` partials of a's group.
__global__ void reduce_groups(const float* __restrict__ ws,
                              float* __restrict__ out,
                              int members, int n_atoms) {
    int i = blockIdx.x * blockDim.x + threadIdx.x;
    if (i >= n_atoms) return;
    int g = i / BUCKET;
    int off = i - g * BUCKET;
    const float* base = ws + ((size_t)g * members) * BUCKET + off;
    float s = 0.0f;
    #pragma unroll 5
    for (int b = 0; b < members; ++b) s += base[(size_t)b * BUCKET];
    out[i] = s;
}

// Fallback (ws far too small): device-scope atomics straight into out. Slow but correct.
__global__ void lj_scatter_direct(const float* __restrict__ dist,
                                  const int* __restrict__ atom_a,
                                  const int* __restrict__ atom_b,
                                  float* __restrict__ out,
                                  int n_edges) {
    int t = blockIdx.x * blockDim.x + threadIdx.x;
    long long e0 = (long long)t * 4;
    if (e0 >= n_edges) return;
    if (e0 + 3 < n_edges) {
        const float4* d4 = (const float4*)(dist) + (size_t)t * 3;
        float4 v0 = d4[0];
        float4 v1 = d4[1];
        float4 v2 = d4[2];
        int4 ia = ((const int4*)atom_a)[t];
        int4 ib = ((const int4*)atom_b)[t];
        float h0 = lj_half_e(v0.x, v0.y, v0.z);
        float h1 = lj_half_e(v0.w, v1.x, v1.y);
        float h2 = lj_half_e(v1.z, v1.w, v2.x);
        float h3 = lj_half_e(v2.y, v2.z, v2.w);
        atomicAdd(&out[ia.x], h0);
        atomicAdd(&out[ib.x], h0);
        atomicAdd(&out[ia.y], h1);
        atomicAdd(&out[ib.y], h1);
        atomicAdd(&out[ia.z], h2);
        atomicAdd(&out[ib.z], h2);
        atomicAdd(&out[ia.w], h3);
        atomicAdd(&out[ib.w], h3);
    } else {
        for (long long e = e0; e < n_edges; ++e) {
            float x = dist[e * 3 + 0];
            float y = dist[e * 3 + 1];
            float z = dist[e * 3 + 2];
            float h = lj_half_e(x, y, z);
            atomicAdd(&out[atom_a[e]], h);
            atomicAdd(&out[atom_b[e]], h);
        }
    }
}

extern "C" void kernel_launch(void* const* d_in, const int* in_sizes, int n_in,
                              void* d_out, int out_size, void* d_ws, size_t ws_size,
                              hipStream_t stream) {
    const float* dist = (const float*)d_in[0];
    const int* atom_a = (const int*)d_in[1];
    const int* atom_b = (const int*)d_in[2];
    float* out = (float*)d_out;

    int n_edges = in_sizes[1];
    int n_atoms = out_size;

    size_t per_member = (size_t)GROUPS * BUCKET * sizeof(float);
    int members = (int)(ws_size / per_member);
    if (members > MAX_MEMBERS) members = MAX_MEMBERS;
    bool range_ok = ((long long)GROUPS * BUCKET >= (long long)n_atoms);

    if (members >= 8 && range_ok) {
        float* ws = (float*)d_ws;
        lj_gather_group<<<GROUPS * members, BLOCK_T, 0, stream>>>(
            dist, atom_a, atom_b, ws, members, n_edges);
        int rblock = 256;
        int rgrid = (n_atoms + rblock - 1) / rblock;
        reduce_groups<<<rgrid, rblock, 0, stream>>>(ws, out, members, n_atoms);
    } else {
        hipMemsetAsync(d_out, 0, (size_t)n_atoms * sizeof(float), stream);
        int n_quads = (n_edges + 3) / 4;
        int block = 256;
        int grid = (n_quads + block - 1) / block;
        lj_scatter_direct<<<grid, block, 0, stream>>>(dist, atom_a, atom_b, out, n_edges);
    }
}